// Round 2
// baseline (565.273 us; speedup 1.0000x reference)
//
#include <hip/hip_runtime.h>

// HashEncoder (Instant-NGP style), MI355X.
// L=16 levels, T=16384 table entries, F=1.
// N_l table derived from exact f32 trace of exp((log512-log16)/15):
// the f32 'b' lands 1 ulp above 2^(1/3), so all l%3==0 levels hit the
// exact power of two. {16,20,25,32,40,50,64,80,101,128,161,203,256,322,406,512}
//
// Exactness contract: bl_idx = floor(x / cube) must be bit-identical to the
// reference (cube = RN(1/N_l), IEEE f32 division). Weights w only need ~1e-3
// accuracy (threshold is 2e-6 absolute on 1e-4-scale outputs), so w = t - floor(t).

#define HE_L 16
#define HE_T 16384
#define HE_NPTS (8 * 262144)
#define HE_BLOCK 512
#define HE_PPT 4
#define HE_PTS_PER_BLOCK (HE_BLOCK * HE_PPT)   // 2048
#define HE_GRID (HE_NPTS / HE_PTS_PER_BLOCK)   // 1024 (exact)

__global__ void __launch_bounds__(HE_BLOCK)
hashenc_kernel(const float* __restrict__ xin,
               const float* __restrict__ tables,
               float* __restrict__ out)
{
    __shared__ float tab[HE_T];   // 64 KiB: current level's table
    const int tid  = threadIdx.x;
    const int base = blockIdx.x * HE_PTS_PER_BLOCK;

    // Load coordinates for this thread's 4 points (coalesced-ish: 12 B stride).
    float px[HE_PPT], py[HE_PPT], pz[HE_PPT];
#pragma unroll
    for (int k = 0; k < HE_PPT; ++k) {
        const int p = base + tid + k * HE_BLOCK;
        px[k] = xin[3 * p + 0];
        py[k] = xin[3 * p + 1];
        pz[k] = xin[3 * p + 2];
    }

    float o[HE_PPT * HE_L];   // 64 VGPRs of outputs; all indices static (full unroll)

#pragma unroll
    for (int lev = 0; lev < HE_L; ++lev) {
        constexpr float Nl_tab[HE_L] = {16.f, 20.f, 25.f, 32.f, 40.f, 50.f, 64.f, 80.f,
                                        101.f, 128.f, 161.f, 203.f, 256.f, 322.f, 406.f, 512.f};
        __syncthreads();   // previous level's gathers done before overwrite
        {
            // Stage level table: 16384 floats = 4096 float4; 512 threads -> 8 iters.
            const float4* __restrict__ src = (const float4*)(tables + lev * HE_T);
            float4* dst = (float4*)tab;
#pragma unroll
            for (int i = 0; i < HE_T / 4 / HE_BLOCK; ++i)
                dst[tid + i * HE_BLOCK] = src[tid + i * HE_BLOCK];
        }
        __syncthreads();

        const float cube = 1.0f / Nl_tab[lev];   // compile-time RN(1/N_l)

#pragma unroll
        for (int k = 0; k < HE_PPT; ++k) {
            // IEEE f32 division — must match reference's floor((x-0)/cube) exactly.
            const float tx = px[k] / cube;
            const float ty = py[k] / cube;
            const float tz = pz[k] / cube;
            const float fx = floorf(tx), fy = floorf(ty), fz = floorf(tz);
            const float wx = tx - fx, wy = ty - fy, wz = tz - fz;  // approx weights (OK)
            const unsigned ux = (unsigned)(int)fx;
            const unsigned uy = (unsigned)(int)fy;
            const unsigned uz = (unsigned)(int)fz;
            const unsigned a0 = ux,                  a1 = ux + 1u;
            const unsigned b0 = uy * 2654435761u,    b1 = b0 + 2654435761u;
            const unsigned c0 = uz * 805459861u,     c1 = c0 + 805459861u;
            // OFFSETS order: k = (dx<<2)|(dy<<1)|dz
            const float v0 = tab[(a0 ^ b0 ^ c0) & (HE_T - 1)];
            const float v1 = tab[(a0 ^ b0 ^ c1) & (HE_T - 1)];
            const float v2 = tab[(a0 ^ b1 ^ c0) & (HE_T - 1)];
            const float v3 = tab[(a0 ^ b1 ^ c1) & (HE_T - 1)];
            const float v4 = tab[(a1 ^ b0 ^ c0) & (HE_T - 1)];
            const float v5 = tab[(a1 ^ b0 ^ c1) & (HE_T - 1)];
            const float v6 = tab[(a1 ^ b1 ^ c0) & (HE_T - 1)];
            const float v7 = tab[(a1 ^ b1 ^ c1) & (HE_T - 1)];
            const float omx = 1.0f - wx, omy = 1.0f - wy, omz = 1.0f - wz;
            const float i0 = v0 * omx + v4 * wx;
            const float i1 = v1 * omx + v5 * wx;
            const float i2 = v2 * omx + v6 * wx;
            const float i3 = v3 * omx + v7 * wx;
            const float j0 = i0 * omy + i2 * wy;
            const float j1 = i1 * omy + i3 * wy;
            o[k * HE_L + lev] = j0 * omz + j1 * wz;
        }
    }

    // Coalesced output: each point's 16 floats are contiguous (64 B = full lines).
#pragma unroll
    for (int k = 0; k < HE_PPT; ++k) {
        const int p = base + tid + k * HE_BLOCK;
        float4* dst = (float4*)(out + HE_L * p);
#pragma unroll
        for (int q = 0; q < 4; ++q)
            dst[q] = make_float4(o[k * HE_L + 4 * q + 0], o[k * HE_L + 4 * q + 1],
                                 o[k * HE_L + 4 * q + 2], o[k * HE_L + 4 * q + 3]);
    }
}

extern "C" void kernel_launch(void* const* d_in, const int* in_sizes, int n_in,
                              void* d_out, int out_size, void* d_ws, size_t ws_size,
                              hipStream_t stream)
{
    const float* x      = (const float*)d_in[0];   // (8, 262144, 3) f32
    const float* tables = (const float*)d_in[1];   // (16, 16384, 1) f32
    float* out = (float*)d_out;                    // (8, 262144, 16) f32
    hashenc_kernel<<<dim3(HE_GRID), dim3(HE_BLOCK), 0, stream>>>(x, tables, out);
}